// Round 13
// baseline (18.175 us; speedup 1.0000x reference)
//
#include <hip/hip_runtime.h>
#include <hip/hip_bf16.h>

#define DX 128
#define DH 128
#define HID 512
#define NB 4096
#define ROWS 16
#define OUTC 129   // 128 v cols + 1 div col

typedef __attribute__((ext_vector_type(4))) float f32x4;
typedef __attribute__((ext_vector_type(4))) float float4v;
typedef __attribute__((ext_vector_type(2))) float float2v;
typedef __attribute__((ext_vector_type(8))) short bf16x8;
typedef __attribute__((ext_vector_type(4))) short bf16x4;
typedef __attribute__((ext_vector_type(2))) short bf16x2;

// RNE float -> bf16 (bit pattern in a short)
__device__ inline short f2bf(float f) {
    unsigned u = __float_as_uint(f);
    unsigned r = (u + 0x7fffu + ((u >> 16) & 1u)) >> 16;
    return (short)r;
}

__device__ inline float fast_tanh(float x) {
    float e = __expf(2.0f * x);
    float r = __builtin_amdgcn_rcpf(e + 1.0f);
    return 1.0f - 2.0f * r;
}

// -------- prep v2 (unchanged, proven): wave-per-tile coalesced repack --------
// W1P layout: [nt(32)][ks(8)][lane(64)][e(8)] -> W1[(ks*32+(l>>4)*8+e), nt*16+(l&15)]
// W2P layout: [nt(8)][ks(16)][lane(64)][e(8)] -> W2[(ks*32+(l>>4)*8+e), nt*16+(l&15)]
__global__ __launch_bounds__(256) void prep_kernel(
    const float* __restrict__ W1, const float* __restrict__ W2,
    float* __restrict__ c, short* __restrict__ w1p, short* __restrict__ w2p)
{
    __shared__ float tile[4][32][17];

    const int tid  = threadIdx.x;
    const int lane = tid & 63;
    const int w    = tid >> 6;
    const int l15  = lane & 15;
    const int l4   = lane >> 4;
    const int W    = blockIdx.x * 4 + w;

    if (W < 256) {                         // w1p tile
        int nt = W >> 3, ks = W & 7;
        int m0 = ks * 32, n0 = nt * 16;
        #pragma unroll
        for (int p = 0; p < 8; ++p) {
            int r = p * 4 + l4;
            tile[w][r][l15] = W1[(m0 + r) * HID + n0 + l15];
        }
    } else if (W < 384) {                  // w2p tile
        int idx = W - 256;
        int nt = idx >> 4, ks = idx & 15;
        int k0 = ks * 32, n0 = nt * 16;
        #pragma unroll
        for (int p = 0; p < 8; ++p) {
            int r = p * 4 + l4;
            tile[w][r][l15] = W2[(k0 + r) * DX + n0 + l15];
        }
    }
    __syncthreads();

    if (W < 256) {
        bf16x8 v;
        #pragma unroll
        for (int e = 0; e < 8; ++e) v[e] = f2bf(tile[w][l4 * 8 + e][l15]);
        *(bf16x8*)&w1p[W * 512 + lane * 8] = v;
    } else if (W < 384) {
        int idx = W - 256;
        bf16x8 v;
        #pragma unroll
        for (int e = 0; e < 8; ++e) v[e] = f2bf(tile[w][l4 * 8 + e][l15]);
        *(bf16x8*)&w2p[idx * 512 + lane * 8] = v;
    } else if (W < 896) {                  // c[k] = sum_i W1[i,k]*W2[k,i]
        int k = W - 384;
        float p = W1[lane * HID + k] * W2[k * DX + lane]
                + W1[(lane + 64) * HID + k] * W2[k * DX + lane + 64];
        for (int m = 1; m < 64; m <<= 1) p += __shfl_xor(p, m, 64);
        if (lane == 0) c[k] = p;
    }
}

// -------- cvf v7: blend-before-GEMM2 + full-K 8-wave GEMM2 (2 barriers, no red) ----
// GEMM1 (swapped): wave w owns hidden cols [w*32,w*32+32); acc = pre^T; lane holds
//   pre^T[k = w*32+j*16+l4*4+q][row = l15].
// epilogue A: a_blend = gs*tanh(pre_h)+(1-gs)*tanh(pre_n) -> ONE ab; blended div partial.
// GEMM2: waves 0..7 full-K=512, out cols [w*16,w*16+16); wave 8 writes div;
//   waves 9..15 retire after barrier 2. No red exchange, no barrier 3.
__global__ __launch_bounds__(1024) void cvf_kernel(
    const float* __restrict__ state, const float* __restrict__ h_,
    const float* __restrict__ hn_, const float* __restrict__ tptr,
    const float* __restrict__ gsptr, const float* __restrict__ W1,
    const float* __restrict__ b1, const float* __restrict__ b2,
    const float* __restrict__ c, const short* __restrict__ w1p,
    const short* __restrict__ w2p, float* __restrict__ out)
{
    __shared__ short xb [ROWS][DX + 8];
    __shared__ short hb [ROWS][DH + 8];
    __shared__ short hnb[ROWS][DH + 8];
    __shared__ short ab [ROWS][HID + 8];     // blended activations (16 KB)
    __shared__ float divp[16][ROWS];         // blended div partials

    const int tid  = threadIdx.x;
    const int lane = tid & 63;
    const int w    = tid >> 6;         // wave 0..15
    const int l15  = lane & 15;
    const int l4   = lane >> 4;
    const int row0 = blockIdx.x * ROWS;
    const float t  = tptr[0];
    const float gs = gsptr[0];
    const float gn = 1.0f - gs;

    // ---- prefetch: all 8 x-part W1 frags + vectorized base fold ----
    bf16x8 bx[2][4];
    f32x4 base[2];
    #pragma unroll
    for (int j = 0; j < 2; ++j) {
        #pragma unroll
        for (int ks = 0; ks < 4; ++ks)
            bx[j][ks] = *(const bf16x8*)&w1p[(((w * 2 + j) * 8 + ks) * 64 + lane) * 8];
        int k0 = w * 32 + j * 16 + l4 * 4;
        float4v bb = *(const float4v*)&b1[k0];
        float4v tw = *(const float4v*)&W1[256 * HID + k0];
        #pragma unroll
        for (int q = 0; q < 4; ++q) base[j][q] = bb[q] + t * tw[q];
    }

    // ---- stage x / h / h_null as bf16 into LDS (1024 threads: 2 floats each) ----
    {
        int r  = tid >> 6;            // 0..15
        int c0 = (tid & 63) * 2;      // 0..126
        const float* sp = state + (row0 + r) * OUTC + c0;   // x = state[:, :128]
        float2v vh = *(const float2v*)(h_  + (row0 + r) * DH + c0);
        float2v vn = *(const float2v*)(hn_ + (row0 + r) * DH + c0);
        bf16x2 sx, sh, sn;
        #pragma unroll
        for (int e = 0; e < 2; ++e) {
            sx[e] = f2bf(sp[e]);
            sh[e] = f2bf(vh[e]);
            sn[e] = f2bf(vn[e]);
        }
        *(bf16x2*)&xb [r][c0] = sx;
        *(bf16x2*)&hb [r][c0] = sh;
        *(bf16x2*)&hnb[r][c0] = sn;
    }
    __syncthreads();

    // ---- GEMM1 (swapped): acc[j] = pre^T[k = w*32+j*16+l4*4+q][row = l15] ----
    f32x4 acc_h[2], acc_n[2];
    {
        bf16x8 ax[4];
        #pragma unroll
        for (int ks = 0; ks < 4; ++ks)
            ax[ks] = *(const bf16x8*)&xb[l15][ks * 32 + l4 * 8];

        f32x4 accx[2];
        #pragma unroll
        for (int j = 0; j < 2; ++j) accx[j] = base[j];
        #pragma unroll
        for (int ks = 0; ks < 4; ++ks)
            #pragma unroll
            for (int j = 0; j < 2; ++j)
                accx[j] = __builtin_amdgcn_mfma_f32_16x16x32_bf16(bx[j][ks], ax[ks], accx[j], 0, 0, 0);

        bf16x8 bh[2][4];
        #pragma unroll
        for (int j = 0; j < 2; ++j)
            #pragma unroll
            for (int ks = 0; ks < 4; ++ks)
                bh[j][ks] = *(const bf16x8*)&w1p[(((w * 2 + j) * 8 + 4 + ks) * 64 + lane) * 8];
        bf16x8 ah[4], an[4];
        #pragma unroll
        for (int ks = 0; ks < 4; ++ks) {
            ah[ks] = *(const bf16x8*)&hb [l15][ks * 32 + l4 * 8];
            an[ks] = *(const bf16x8*)&hnb[l15][ks * 32 + l4 * 8];
        }

        #pragma unroll
        for (int j = 0; j < 2; ++j) { acc_h[j] = accx[j]; acc_n[j] = accx[j]; }
        #pragma unroll
        for (int ks = 0; ks < 4; ++ks)
            #pragma unroll
            for (int j = 0; j < 2; ++j) {
                acc_h[j] = __builtin_amdgcn_mfma_f32_16x16x32_bf16(bh[j][ks], ah[ks], acc_h[j], 0, 0, 0);
                acc_n[j] = __builtin_amdgcn_mfma_f32_16x16x32_bf16(bh[j][ks], an[ks], acc_n[j], 0, 0, 0);
            }
    }

    // ---- prefetch first half of GEMM2 W2 frags (waves 0..7): hides under epilogue A ----
    bf16x8 b2f[8];
    if (w < 8) {
        #pragma unroll
        for (int ks = 0; ks < 8; ++ks)
            b2f[ks] = *(const bf16x8*)&w2p[((w * 16 + ks) * 64 + lane) * 8];
    }

    // ---- epilogue A: blended a -> ab (b64); blended div partial ----
    float dp = 0.f;
    #pragma unroll
    for (int j = 0; j < 2; ++j) {
        int k0 = w * 32 + j * 16 + l4 * 4;
        float4v c4 = *(const float4v*)&c[k0];
        bf16x4 pb;
        #pragma unroll
        for (int q = 0; q < 4; ++q) {
            float a1 = fast_tanh(acc_h[j][q]);
            float a2 = fast_tanh(acc_n[j][q]);
            pb[q] = f2bf(gs * a1 + gn * a2);
            dp += (gs * (1.f - a1 * a1) + gn * (1.f - a2 * a2)) * c4[q];
        }
        *(bf16x4*)&ab[l15][k0] = pb;
    }
    dp += __shfl_xor(dp, 16, 64);
    dp += __shfl_xor(dp, 32, 64);
    if (l4 == 0) divp[w][l15] = dp;
    __syncthreads();

    // ---- GEMM2: waves 0..7, full K=512, out cols [w*16, w*16+16) ----
    if (w < 8) {
        f32x4 av = (f32x4){0, 0, 0, 0};
        #pragma unroll
        for (int ks = 0; ks < 8; ++ks) {
            bf16x8 af = *(const bf16x8*)&ab[l15][ks * 32 + l4 * 8];
            av = __builtin_amdgcn_mfma_f32_16x16x32_bf16(af, b2f[ks], av, 0, 0, 0);
        }
        bf16x8 b2g[8];
        #pragma unroll
        for (int ks = 0; ks < 8; ++ks)
            b2g[ks] = *(const bf16x8*)&w2p[((w * 16 + 8 + ks) * 64 + lane) * 8];
        #pragma unroll
        for (int ks = 0; ks < 8; ++ks) {
            bf16x8 af = *(const bf16x8*)&ab[l15][(8 + ks) * 32 + l4 * 8];
            av = __builtin_amdgcn_mfma_f32_16x16x32_bf16(af, b2g[ks], av, 0, 0, 0);
        }
        int col = w * 16 + l15;
        float bb = b2[col];
        #pragma unroll
        for (int q = 0; q < 4; ++q) {
            int r = l4 * 4 + q;
            out[(row0 + r) * OUTC + col] = av[q] + bb;
        }
    } else if (w == 8 && lane < ROWS) {
        // ---- div: sum 16 blended wave partials, write col 128 ----
        float d = 0.f;
        #pragma unroll
        for (int ww = 0; ww < 16; ++ww) d += divp[ww][lane];
        out[(row0 + lane) * OUTC + DX] = d;
    }
}

extern "C" void kernel_launch(void* const* d_in, const int* in_sizes, int n_in,
                              void* d_out, int out_size, void* d_ws, size_t ws_size,
                              hipStream_t stream) {
    const float* state = (const float*)d_in[0];
    const float* h     = (const float*)d_in[1];
    const float* hn    = (const float*)d_in[2];
    const float* t     = (const float*)d_in[3];
    const float* gs    = (const float*)d_in[4];
    const float* W1    = (const float*)d_in[5];
    const float* b1    = (const float*)d_in[6];
    const float* W2    = (const float*)d_in[7];
    const float* b2    = (const float*)d_in[8];
    float* out = (float*)d_out;

    // workspace layout: c (512 f32) | W1P (131072 bf16) | W2P (65536 bf16)  ~= 390 KB
    float* c   = (float*)d_ws;
    short* w1p = (short*)((char*)d_ws + 2048);
    short* w2p = (short*)((char*)d_ws + 2048 + 262144);

    prep_kernel<<<224, 256, 0, stream>>>(W1, W2, c, w1p, w2p);
    cvf_kernel<<<NB / ROWS, 1024, 0, stream>>>(state, h, hn, t, gs, W1, b1, b2, c, w1p, w2p, out);
}

// Round 14
// 17.553 us; speedup vs baseline: 1.0354x; 1.0354x over previous
//
#include <hip/hip_runtime.h>
#include <hip/hip_bf16.h>

#define DX 128
#define DH 128
#define HID 512
#define NB 4096
#define ROWS 16
#define OUTC 129   // 128 v cols + 1 div col

typedef __attribute__((ext_vector_type(4))) float f32x4;
typedef __attribute__((ext_vector_type(4))) float float4v;
typedef __attribute__((ext_vector_type(2))) float float2v;
typedef __attribute__((ext_vector_type(8))) short bf16x8;
typedef __attribute__((ext_vector_type(4))) short bf16x4;
typedef __attribute__((ext_vector_type(2))) short bf16x2;

// RNE float -> bf16 (bit pattern in a short)
__device__ inline short f2bf(float f) {
    unsigned u = __float_as_uint(f);
    unsigned r = (u + 0x7fffu + ((u >> 16) & 1u)) >> 16;
    return (short)r;
}

__device__ inline float fast_tanh(float x) {
    float e = __expf(2.0f * x);
    float r = __builtin_amdgcn_rcpf(e + 1.0f);
    return 1.0f - 2.0f * r;
}

// -------- prep v3: DIRECT fragment gather (no LDS, no barrier) --------
// Same 4-lines-per-instruction coalescing as the staged version, one hop less.
// W1P layout: [nt(32)][ks(8)][lane(64)][e(8)] -> W1[(ks*32+(l>>4)*8+e), nt*16+(l&15)]
// W2P layout: [nt(8)][ks(16)][lane(64)][e(8)] -> W2[(ks*32+(l>>4)*8+e), nt*16+(l&15)]
__global__ __launch_bounds__(256) void prep_kernel(
    const float* __restrict__ W1, const float* __restrict__ W2,
    float* __restrict__ c, short* __restrict__ w1p, short* __restrict__ w2p)
{
    const int tid  = threadIdx.x;
    const int lane = tid & 63;
    const int w    = tid >> 6;
    const int l15  = lane & 15;
    const int l4   = lane >> 4;
    const int W    = blockIdx.x * 4 + w;

    if (W < 256) {                         // w1p tile: direct gather + pack
        int nt = W >> 3, ks = W & 7;
        const float* p = W1 + (ks * 32 + l4 * 8) * HID + nt * 16 + l15;
        bf16x8 v;
        #pragma unroll
        for (int e = 0; e < 8; ++e) v[e] = f2bf(p[e * HID]);
        *(bf16x8*)&w1p[W * 512 + lane * 8] = v;
    } else if (W < 384) {                  // w2p tile: direct gather + pack
        int idx = W - 256;
        int nt = idx >> 4, ks = idx & 15;
        const float* p = W2 + (ks * 32 + l4 * 8) * DX + nt * 16 + l15;
        bf16x8 v;
        #pragma unroll
        for (int e = 0; e < 8; ++e) v[e] = f2bf(p[e * DX]);
        *(bf16x8*)&w2p[idx * 512 + lane * 8] = v;
    } else if (W < 896) {                  // c[k] = sum_i W1[i,k]*W2[k,i]
        int k = W - 384;
        float p = W1[lane * HID + k] * W2[k * DX + lane]
                + W1[(lane + 64) * HID + k] * W2[k * DX + lane + 64];
        for (int m = 1; m < 64; m <<= 1) p += __shfl_xor(p, m, 64);
        if (lane == 0) c[k] = p;
    }
}

// -------- cvf v6 (R12-exact, best measured 17.57): blend-before-GEMM2 --------
// GEMM1 (swapped): wave w owns hidden cols [w*32,w*32+32); acc = pre^T; lane holds
//   pre^T[k = w*32+j*16+l4*4+q][row = l15].
// epilogue A: a_blend = gs*tanh(pre_h)+(1-gs)*tanh(pre_n) -> ONE ab; blended div partial.
// GEMM2 (K-split, single accumulator): wave pair (2m,2m+1) -> out cols [m*16,m*16+16);
//   even wave K=0..255, odd K=256..511; red exchange halved.
// Div finalize: wave 1, 64-lane parallel (4 reads + 2 shfl).
__global__ __launch_bounds__(1024) void cvf_kernel(
    const float* __restrict__ state, const float* __restrict__ h_,
    const float* __restrict__ hn_, const float* __restrict__ tptr,
    const float* __restrict__ gsptr, const float* __restrict__ W1,
    const float* __restrict__ b1, const float* __restrict__ b2,
    const float* __restrict__ c, const short* __restrict__ w1p,
    const short* __restrict__ w2p, float* __restrict__ out)
{
    __shared__ short xb [ROWS][DX + 8];
    __shared__ short hb [ROWS][DH + 8];
    __shared__ short hnb[ROWS][DH + 8];
    __shared__ short ab [ROWS][HID + 8];     // blended activations (16 KB)
    __shared__ float divp[16][ROWS];         // blended div partials
    __shared__ float red[8][64][4];          // K-split partial exchange

    const int tid  = threadIdx.x;
    const int lane = tid & 63;
    const int w    = tid >> 6;         // wave 0..15
    const int l15  = lane & 15;
    const int l4   = lane >> 4;
    const int row0 = blockIdx.x * ROWS;
    const float t  = tptr[0];
    const float gs = gsptr[0];
    const float gn = 1.0f - gs;

    // ---- prefetch: all 8 x-part W1 frags + vectorized base fold ----
    bf16x8 bx[2][4];
    f32x4 base[2];
    #pragma unroll
    for (int j = 0; j < 2; ++j) {
        #pragma unroll
        for (int ks = 0; ks < 4; ++ks)
            bx[j][ks] = *(const bf16x8*)&w1p[(((w * 2 + j) * 8 + ks) * 64 + lane) * 8];
        int k0 = w * 32 + j * 16 + l4 * 4;
        float4v bb = *(const float4v*)&b1[k0];
        float4v tw = *(const float4v*)&W1[256 * HID + k0];
        #pragma unroll
        for (int q = 0; q < 4; ++q) base[j][q] = bb[q] + t * tw[q];
    }

    // ---- stage x / h / h_null as bf16 into LDS (1024 threads: 2 floats each) ----
    {
        int r  = tid >> 6;            // 0..15
        int c0 = (tid & 63) * 2;      // 0..126
        const float* sp = state + (row0 + r) * OUTC + c0;   // x = state[:, :128]
        float2v vh = *(const float2v*)(h_  + (row0 + r) * DH + c0);
        float2v vn = *(const float2v*)(hn_ + (row0 + r) * DH + c0);
        bf16x2 sx, sh, sn;
        #pragma unroll
        for (int e = 0; e < 2; ++e) {
            sx[e] = f2bf(sp[e]);
            sh[e] = f2bf(vh[e]);
            sn[e] = f2bf(vn[e]);
        }
        *(bf16x2*)&xb [r][c0] = sx;
        *(bf16x2*)&hb [r][c0] = sh;
        *(bf16x2*)&hnb[r][c0] = sn;
    }
    __syncthreads();

    // ---- GEMM1 (swapped): acc[j] = pre^T[k = w*32+j*16+l4*4+q][row = l15] ----
    f32x4 acc_h[2], acc_n[2];
    {
        bf16x8 ax[4];
        #pragma unroll
        for (int ks = 0; ks < 4; ++ks)
            ax[ks] = *(const bf16x8*)&xb[l15][ks * 32 + l4 * 8];

        f32x4 accx[2];
        #pragma unroll
        for (int j = 0; j < 2; ++j) accx[j] = base[j];
        #pragma unroll
        for (int ks = 0; ks < 4; ++ks)
            #pragma unroll
            for (int j = 0; j < 2; ++j)
                accx[j] = __builtin_amdgcn_mfma_f32_16x16x32_bf16(bx[j][ks], ax[ks], accx[j], 0, 0, 0);

        bf16x8 bh[2][4];
        #pragma unroll
        for (int j = 0; j < 2; ++j)
            #pragma unroll
            for (int ks = 0; ks < 4; ++ks)
                bh[j][ks] = *(const bf16x8*)&w1p[(((w * 2 + j) * 8 + 4 + ks) * 64 + lane) * 8];
        bf16x8 ah[4], an[4];
        #pragma unroll
        for (int ks = 0; ks < 4; ++ks) {
            ah[ks] = *(const bf16x8*)&hb [l15][ks * 32 + l4 * 8];
            an[ks] = *(const bf16x8*)&hnb[l15][ks * 32 + l4 * 8];
        }

        #pragma unroll
        for (int j = 0; j < 2; ++j) { acc_h[j] = accx[j]; acc_n[j] = accx[j]; }
        #pragma unroll
        for (int ks = 0; ks < 4; ++ks)
            #pragma unroll
            for (int j = 0; j < 2; ++j) {
                acc_h[j] = __builtin_amdgcn_mfma_f32_16x16x32_bf16(bh[j][ks], ah[ks], acc_h[j], 0, 0, 0);
                acc_n[j] = __builtin_amdgcn_mfma_f32_16x16x32_bf16(bh[j][ks], an[ks], acc_n[j], 0, 0, 0);
            }
    }

    // ---- prefetch this wave's GEMM2 W2 frags (K-split half): hides under epilogue A ----
    const int nt2 = w >> 1;
    const int ks0 = (w & 1) * 8;
    bf16x8 b2f[8];
    #pragma unroll
    for (int ks = 0; ks < 8; ++ks)
        b2f[ks] = *(const bf16x8*)&w2p[((nt2 * 16 + ks0 + ks) * 64 + lane) * 8];

    // ---- epilogue A: blended a -> ab (b64); blended div partial ----
    float dp = 0.f;
    #pragma unroll
    for (int j = 0; j < 2; ++j) {
        int k0 = w * 32 + j * 16 + l4 * 4;
        float4v c4 = *(const float4v*)&c[k0];
        bf16x4 pb;
        #pragma unroll
        for (int q = 0; q < 4; ++q) {
            float a1 = fast_tanh(acc_h[j][q]);
            float a2 = fast_tanh(acc_n[j][q]);
            pb[q] = f2bf(gs * a1 + gn * a2);
            dp += (gs * (1.f - a1 * a1) + gn * (1.f - a2 * a2)) * c4[q];
        }
        *(bf16x4*)&ab[l15][k0] = pb;
    }
    dp += __shfl_xor(dp, 16, 64);
    dp += __shfl_xor(dp, 32, 64);
    if (l4 == 0) divp[w][l15] = dp;
    __syncthreads();

    // ---- GEMM2 (K-split, single acc): wave pair (2m,2m+1) -> cols [m*16,m*16+16) ----
    f32x4 av = (f32x4){0, 0, 0, 0};
    #pragma unroll
    for (int ks = 0; ks < 8; ++ks) {
        bf16x8 af = *(const bf16x8*)&ab[l15][(ks0 + ks) * 32 + l4 * 8];
        av = __builtin_amdgcn_mfma_f32_16x16x32_bf16(af, b2f[ks], av, 0, 0, 0);
    }
    if (w & 1) {
        #pragma unroll
        for (int q = 0; q < 4; ++q) red[nt2][lane][q] = av[q];
    }
    __syncthreads();

    // ---- epilogue B: even waves combine partials + bias, write v ----
    if (!(w & 1)) {
        int col = nt2 * 16 + l15;
        float bb = b2[col];
        #pragma unroll
        for (int q = 0; q < 4; ++q) {
            int r = l4 * 4 + q;
            out[(row0 + r) * OUTC + col] = av[q] + red[nt2][lane][q] + bb;
        }
    } else if (w == 1) {
        // ---- div: 64-lane parallel sum of 16 wave partials, write col 128 ----
        float d = divp[l4 * 4 + 0][l15] + divp[l4 * 4 + 1][l15]
                + divp[l4 * 4 + 2][l15] + divp[l4 * 4 + 3][l15];
        d += __shfl_xor(d, 16, 64);
        d += __shfl_xor(d, 32, 64);
        if (l4 == 0)
            out[(row0 + l15) * OUTC + DX] = d;
    }
}

extern "C" void kernel_launch(void* const* d_in, const int* in_sizes, int n_in,
                              void* d_out, int out_size, void* d_ws, size_t ws_size,
                              hipStream_t stream) {
    const float* state = (const float*)d_in[0];
    const float* h     = (const float*)d_in[1];
    const float* hn    = (const float*)d_in[2];
    const float* t     = (const float*)d_in[3];
    const float* gs    = (const float*)d_in[4];
    const float* W1    = (const float*)d_in[5];
    const float* b1    = (const float*)d_in[6];
    const float* W2    = (const float*)d_in[7];
    const float* b2    = (const float*)d_in[8];
    float* out = (float*)d_out;

    // workspace layout: c (512 f32) | W1P (131072 bf16) | W2P (65536 bf16)  ~= 390 KB
    float* c   = (float*)d_ws;
    short* w1p = (short*)((char*)d_ws + 2048);
    short* w2p = (short*)((char*)d_ws + 2048 + 262144);

    prep_kernel<<<224, 256, 0, stream>>>(W1, W2, c, w1p, w2p);
    cvf_kernel<<<NB / ROWS, 1024, 0, stream>>>(state, h, hn, t, gs, W1, b1, b2, c, w1p, w2p, out);
}